// Round 5
// baseline (213.097 us; speedup 1.0000x reference)
//
#include <hip/hip_runtime.h>
#include <hip/hip_bf16.h>

#define I_DIM  512
#define O_DIM  512
#define NBATCH 1024
#define NSPL   8            // spline coeffs per input channel
#define KPI    12           // K slots per input channel: 8 spline + s_hi,s_hi,s_lo,0
#define KDIM   (I_DIM * KPI)   // 6144
#define NGRID  12           // extended grid points per channel

#define SPLITK 4
#define KSEG   (KDIM / SPLITK) // 1536
#define BK     64              // bf16 elems per LDS row; 128 B
#define BM     64
#define BN     64
#define NT     (KSEG / BK)     // 24 K-iterations

typedef __attribute__((ext_vector_type(8))) short bf16x8;
typedef __attribute__((ext_vector_type(4))) float f32x4;

// ---------------------------------------------------------------------------
// async global->LDS 16B: dest = wave-uniform base + lane*16 (m97/m104 semantics)
// ---------------------------------------------------------------------------
__device__ __forceinline__ void gload_lds16(const __hip_bfloat16* g, __hip_bfloat16* l) {
    __builtin_amdgcn_global_load_lds(
        (const __attribute__((address_space(1))) void*)g,
        (__attribute__((address_space(3))) void*)l, 16, 0, 0);
}

// ---------------------------------------------------------------------------
// Feature row: F[b][i*12+slot] = [B0..B7, s_hi, s_hi, s_lo, 0] (bf16).
// Paired with Wt slots [spline*8, w_hi, w_lo, w_hi, 0]:
//   s_hi*w_hi + s_hi*w_lo + s_lo*w_hi ~= silu(x)*sb  (rel err ~2^-17)
// ---------------------------------------------------------------------------
__device__ __forceinline__ void features_core(float xv, const float* __restrict__ grid,
                                              int i, __hip_bfloat16* __restrict__ dst) {
    float g[NGRID];
#pragma unroll
    for (int j = 0; j < NGRID; ++j) g[j] = grid[i * NGRID + j];

    float B[NGRID - 1];
#pragma unroll
    for (int j = 0; j < NGRID - 1; ++j)
        B[j] = (xv >= g[j] && xv < g[j + 1]) ? 1.0f : 0.0f;
#pragma unroll
    for (int p = 1; p <= 3; ++p) {
#pragma unroll
        for (int j = 0; j < NGRID - 1 - p; ++j) {
            B[j] = (xv - g[j]) / (g[j + p] - g[j]) * B[j]
                 + (g[j + p + 1] - xv) / (g[j + p + 1] - g[j + 1]) * B[j + 1];
        }
    }
    float s = xv / (1.0f + __expf(-xv));  // silu
    __hip_bfloat16 shi = __float2bfloat16(s);
    __hip_bfloat16 slo = __float2bfloat16(s - __bfloat162float(shi));

    __align__(16) __hip_bfloat16 row[KPI];
#pragma unroll
    for (int k = 0; k < NSPL; ++k) row[k] = __float2bfloat16(B[k]);
    row[8]  = shi;
    row[9]  = shi;
    row[10] = slo;
    row[11] = __float2bfloat16(0.0f);

    uint2* d = (uint2*)dst;
    const uint2* srow = (const uint2*)row;
    d[0] = srow[0]; d[1] = srow[1]; d[2] = srow[2];
}

__device__ __forceinline__ void wt_row_core(const float* __restrict__ coef,
                                            const float* __restrict__ sb,
                                            const float* __restrict__ sp,
                                            int i, int o,
                                            __hip_bfloat16* __restrict__ W) {
    float sbv = sb[i * O_DIM + o];
    float spv = sp[i * O_DIM + o];
    const float* cf = coef + (size_t)(i * O_DIM + o) * NSPL;
    __align__(16) __hip_bfloat16 row[KPI];
#pragma unroll
    for (int k = 0; k < NSPL; ++k) row[k] = __float2bfloat16(spv * cf[k]);
    __hip_bfloat16 whi = __float2bfloat16(sbv);
    __hip_bfloat16 wlo = __float2bfloat16(sbv - __bfloat162float(whi));
    row[8]  = whi;
    row[9]  = wlo;
    row[10] = whi;
    row[11] = __float2bfloat16(0.0f);
    uint2* dst = (uint2*)(W + (size_t)o * KDIM + i * KPI);
    const uint2* src = (const uint2*)row;
    dst[0] = src[0]; dst[1] = src[1]; dst[2] = src[2];
}

// ---------------------------------------------------------------------------
// prep: one launch for Wt-build (all 3 layers) + layer-0 features.
// Wt job: per block a (64 i x 4 o) tile of one layer; lane map i=i0+(t>>2),
// o=o0+(t&3) -> 4 consecutive lanes read one FULL 128B line of coef.
// ---------------------------------------------------------------------------
#define WT_BLOCKS   3072   // 3 layers x (8 i-tiles x 128 o-tiles)
#define FEAT_BLOCKS 2048   // NBATCH*I_DIM / 256
__global__ __launch_bounds__(256)
void prep_kernel(const float* __restrict__ x0, const float* __restrict__ gr0,
                 const float* __restrict__ c0, const float* __restrict__ sb0, const float* __restrict__ sp0,
                 const float* __restrict__ c1, const float* __restrict__ sb1, const float* __restrict__ sp1,
                 const float* __restrict__ c2, const float* __restrict__ sb2, const float* __restrict__ sp2,
                 __hip_bfloat16* __restrict__ Wt,   // [3][O_DIM][KDIM]
                 __hip_bfloat16* __restrict__ F) {  // [NBATCH][KDIM]
    int b = blockIdx.x;
    int t = threadIdx.x;
    if (b < WT_BLOCKS) {
        int l   = b >> 10;            // 0..2
        int rem = b & 1023;
        int i0  = (rem & 7) * 64;     // 8 i-tiles
        int o0  = (rem >> 3) * 4;     // 128 o-tiles
        const float* coef = l == 0 ? c0  : (l == 1 ? c1  : c2);
        const float* sb   = l == 0 ? sb0 : (l == 1 ? sb1 : sb2);
        const float* sp   = l == 0 ? sp0 : (l == 1 ? sp1 : sp2);
        wt_row_core(coef, sb, sp, i0 + (t >> 2), o0 + (t & 3),
                    Wt + (size_t)l * O_DIM * KDIM);
    } else {
        int e = (b - WT_BLOCKS) * 256 + t;   // b*512+i over [0, NBATCH*I_DIM)
        features_core(x0[e], gr0, e & (I_DIM - 1), F + (size_t)e * KPI);
    }
}

// ---------------------------------------------------------------------------
// featsum: x = sum of SPLITK partials, then features. reduce: final splitK sum.
// ---------------------------------------------------------------------------
__global__ __launch_bounds__(256)
void build_features_sum(const float* __restrict__ P,  // [SPLITK][NBATCH*I_DIM]
                        const float* __restrict__ grid,
                        __hip_bfloat16* __restrict__ F) {
    int tid = blockIdx.x * blockDim.x + threadIdx.x;
    float xv = 0.f;
#pragma unroll
    for (int s = 0; s < SPLITK; ++s) xv += P[(size_t)s * NBATCH * I_DIM + tid];
    features_core(xv, grid, tid & (I_DIM - 1), F + (size_t)tid * KPI);
}

__global__ __launch_bounds__(256)
void reduce_out(const float* __restrict__ P, float* __restrict__ out) {
    int tid = blockIdx.x * blockDim.x + threadIdx.x;
    float v = 0.f;
#pragma unroll
    for (int s = 0; s < SPLITK; ++s) v += P[(size_t)s * NBATCH * O_DIM + tid];
    out[tid] = v;
}

// ---------------------------------------------------------------------------
// GEMM: P[ks][b,o] = sum_{k in seg ks} F[b,k] * Wt[o][k]   (bf16 MFMA, fp32 acc)
// R5: double-buffered LDS pipeline (T3 minimum 2-phase recipe): stage tile
// t+1 BEFORE computing tile t; ONE __syncthreads() per iteration, whose
// implicit vmcnt(0) drain lands AFTER compute -> global-load latency hides
// under ds_read+MFMA. Indexing byte-identical to R4 (verified): splitK=4,
// BM=BN=64, 4 waves in 2x2, wave tile 32x32 (acc[2][2]), XOR-swizzled LDS.
// Loop unrolled x2 so LDS buffer bases are compile-time.
// ---------------------------------------------------------------------------
__global__ __launch_bounds__(256)
void gemm_kernel(const __hip_bfloat16* __restrict__ A,   // [NBATCH][KDIM]
                 const __hip_bfloat16* __restrict__ Wt,  // [O_DIM][KDIM]
                 float* __restrict__ P) {                // [SPLITK][NBATCH][O_DIM]
    __shared__ __hip_bfloat16 lA[2][BM * BK];   // 2 x 8 KB
    __shared__ __hip_bfloat16 lB[2][BN * BK];   // 2 x 8 KB

    int bm = blockIdx.x;        // 0..15
    int bn = blockIdx.y;        // 0..7
    int ks = blockIdx.z;        // 0..3
    int tid = threadIdx.x;
    int lane = tid & 63;
    int wave = tid >> 6;        // 0..3
    int wr = (wave & 1) * 32;
    int wc = (wave >> 1) * 32;
    int q  = lane >> 4;         // 0..3
    int ln = lane & 15;

    f32x4 acc[2][2];
#pragma unroll
    for (int a = 0; a < 2; ++a)
#pragma unroll
        for (int b = 0; b < 2; ++b) acc[a][b] = (f32x4){0.f, 0.f, 0.f, 0.f};

    const __hip_bfloat16* Abase = A  + (size_t)(bm * BM) * KDIM + ks * KSEG;
    const __hip_bfloat16* Bbase = Wt + (size_t)(bn * BN) * KDIM + ks * KSEG;

    // staging lane map (verified R4): chunk cc covers 64 rows x 8 chunks;
    // row r = cc>>3, swizzled pos = cc&7, source chunk j = (cc&7)^(r&7).
    int cc0 = wave * 128 + lane;
    int cc1 = cc0 + 64;
    int r0 = cc0 >> 3, j0 = (cc0 & 7) ^ (r0 & 7);
    int r1 = cc1 >> 3, j1 = (cc1 & 7) ^ (r1 & 7);
    size_t offA0 = (size_t)r0 * KDIM + j0 * 8;
    size_t offA1 = (size_t)r1 * KDIM + j1 * 8;
    int ldst0 = (wave * 128) * 8;        // LDS elem offset, call 0
    int ldst1 = (wave * 128 + 64) * 8;   // call 1

#define STAGE(buf, kt)                                                        \
    do {                                                                      \
        gload_lds16(Abase + offA0 + (kt), &lA[buf][ldst0]);                   \
        gload_lds16(Abase + offA1 + (kt), &lA[buf][ldst1]);                   \
        gload_lds16(Bbase + offA0 + (kt), &lB[buf][ldst0]);                   \
        gload_lds16(Bbase + offA1 + (kt), &lB[buf][ldst1]);                   \
    } while (0)

#define COMPUTE(buf)                                                          \
    do {                                                                      \
        _Pragma("unroll")                                                     \
        for (int kh = 0; kh < 2; ++kh) {                                      \
            bf16x8 af[2], bfr[2];                                             \
            _Pragma("unroll")                                                 \
            for (int rt = 0; rt < 2; ++rt) {                                  \
                int row = wr + rt * 16 + ln;                                  \
                af[rt] = *(const bf16x8*)(&lA[buf][0] + row * BK +            \
                                          (((kh * 4 + q) ^ (row & 7)) * 8));  \
            }                                                                 \
            _Pragma("unroll")                                                 \
            for (int ct = 0; ct < 2; ++ct) {                                  \
                int row = wc + ct * 16 + ln;                                  \
                bfr[ct] = *(const bf16x8*)(&lB[buf][0] + row * BK +           \
                                           (((kh * 4 + q) ^ (row & 7)) * 8)); \
            }                                                                 \
            _Pragma("unroll")                                                 \
            for (int rt = 0; rt < 2; ++rt)                                    \
                _Pragma("unroll")                                             \
                for (int ct = 0; ct < 2; ++ct)                                \
                    acc[rt][ct] = __builtin_amdgcn_mfma_f32_16x16x32_bf16(    \
                        af[rt], bfr[ct], acc[rt][ct], 0, 0, 0);               \
        }                                                                     \
    } while (0)

    STAGE(0, 0);
    __syncthreads();                      // implicit vmcnt(0): tile 0 landed

    for (int t = 0; t < NT; t += 2) {
        // tile t in buf0; prefetch t+1 into buf1, then compute t.
        STAGE(1, (t + 1) * BK);           // t+1 <= NT-1 always (NT even)
        COMPUTE(0);
        __syncthreads();                  // drains t+1 loads after compute
        // tile t+1 in buf1; prefetch t+2 into buf0 (unless done).
        if (t + 2 < NT) STAGE(0, (t + 2) * BK);
        COMPUTE(1);
        __syncthreads();
    }
#undef STAGE
#undef COMPUTE

    // epilogue: C/D layout col = lane&15, row = quad*4 + reg (round-0 verified)
    float* Pp = P + (size_t)ks * NBATCH * O_DIM;
    int orow = bm * BM + wr;
    int ocol = bn * BN + wc + ln;
#pragma unroll
    for (int rt = 0; rt < 2; ++rt)
#pragma unroll
        for (int ct = 0; ct < 2; ++ct)
#pragma unroll
            for (int r = 0; r < 4; ++r)
                Pp[(size_t)(orow + rt * 16 + q * 4 + r) * O_DIM + ocol + ct * 16]
                    = acc[rt][ct][r];
}

// ---------------------------------------------------------------------------
extern "C" void kernel_launch(void* const* d_in, const int* in_sizes, int n_in,
                              void* d_out, int out_size, void* d_ws, size_t ws_size,
                              hipStream_t stream) {
    const float* x0  = (const float*)d_in[0];
    const float* gr0 = (const float*)d_in[1];
    const float* c0  = (const float*)d_in[2];
    const float* sb0 = (const float*)d_in[3];
    const float* sp0 = (const float*)d_in[4];
    const float* gr1 = (const float*)d_in[5];
    const float* c1  = (const float*)d_in[6];
    const float* sb1 = (const float*)d_in[7];
    const float* sp1 = (const float*)d_in[8];
    const float* gr2 = (const float*)d_in[9];
    const float* c2  = (const float*)d_in[10];
    const float* sb2 = (const float*)d_in[11];
    const float* sp2 = (const float*)d_in[12];

    char* ws = (char*)d_ws;
    const size_t wt_bytes = (size_t)O_DIM * KDIM * sizeof(__hip_bfloat16);   // 6.3 MB/layer
    const size_t f_bytes  = (size_t)NBATCH * KDIM * sizeof(__hip_bfloat16);  // 12.6 MB
    __hip_bfloat16* Wt = (__hip_bfloat16*)ws;                  // 3 layers contiguous
    __hip_bfloat16* F  = (__hip_bfloat16*)(ws + 3 * wt_bytes);
    float* P = (float*)(ws + 3 * wt_bytes + f_bytes);          // [4][1024][512] = 8.4 MB
    float* out = (float*)d_out;

    prep_kernel<<<WT_BLOCKS + FEAT_BLOCKS, 256, 0, stream>>>(
        x0, gr0, c0, sb0, sp0, c1, sb1, sp1, c2, sb2, sp2, Wt, F);

    gemm_kernel<<<dim3(NBATCH / BM, O_DIM / BN, SPLITK), 256, 0, stream>>>(F, Wt, P);

    build_features_sum<<<(NBATCH * I_DIM) / 256, 256, 0, stream>>>(P, gr1, F);
    gemm_kernel<<<dim3(NBATCH / BM, O_DIM / BN, SPLITK), 256, 0, stream>>>(
        F, Wt + (size_t)O_DIM * KDIM, P);

    build_features_sum<<<(NBATCH * I_DIM) / 256, 256, 0, stream>>>(P, gr2, F);
    gemm_kernel<<<dim3(NBATCH / BM, O_DIM / BN, SPLITK), 256, 0, stream>>>(
        F, Wt + (size_t)2 * O_DIM * KDIM, P);

    reduce_out<<<(NBATCH * O_DIM) / 256, 256, 0, stream>>>(P, out);
}

// Round 6
// 205.642 us; speedup vs baseline: 1.0363x; 1.0363x over previous
//
#include <hip/hip_runtime.h>
#include <hip/hip_bf16.h>

#define I_DIM  512
#define O_DIM  512
#define NBATCH 1024
#define NSPL   8            // spline coeffs per input channel
#define KPI    12           // K slots per input channel: 8 spline + s_hi,s_hi,s_lo,0
#define KDIM   (I_DIM * KPI)   // 6144
#define NGRID  12           // extended grid points per channel

#define SPLITK 8
#define KSEG   (KDIM / SPLITK) // 768
#define BK     64              // bf16 elems per LDS row; 128 B
#define BM     128
#define BN     64

typedef __attribute__((ext_vector_type(8))) short bf16x8;
typedef __attribute__((ext_vector_type(4))) float f32x4;

// ---------------------------------------------------------------------------
// async global->LDS 16B: dest = wave-uniform base + lane*16 (m97/m104 semantics)
// ---------------------------------------------------------------------------
__device__ __forceinline__ void gload_lds16(const __hip_bfloat16* g, __hip_bfloat16* l) {
    __builtin_amdgcn_global_load_lds(
        (const __attribute__((address_space(1))) void*)g,
        (__attribute__((address_space(3))) void*)l, 16, 0, 0);
}

// ---------------------------------------------------------------------------
// Feature row: F[b][i*12+slot] = [B0..B7, s_hi, s_hi, s_lo, 0] (bf16).
// Paired with Wt slots [spline*8, w_hi, w_lo, w_hi, 0]:
//   s_hi*w_hi + s_hi*w_lo + s_lo*w_hi ~= silu(x)*sb  (rel err ~2^-17)
// ---------------------------------------------------------------------------
__device__ __forceinline__ void features_core(float xv, const float* __restrict__ grid,
                                              int i, __hip_bfloat16* __restrict__ dst) {
    float g[NGRID];
#pragma unroll
    for (int j = 0; j < NGRID; ++j) g[j] = grid[i * NGRID + j];

    float B[NGRID - 1];
#pragma unroll
    for (int j = 0; j < NGRID - 1; ++j)
        B[j] = (xv >= g[j] && xv < g[j + 1]) ? 1.0f : 0.0f;
#pragma unroll
    for (int p = 1; p <= 3; ++p) {
#pragma unroll
        for (int j = 0; j < NGRID - 1 - p; ++j) {
            B[j] = (xv - g[j]) / (g[j + p] - g[j]) * B[j]
                 + (g[j + p + 1] - xv) / (g[j + p + 1] - g[j + 1]) * B[j + 1];
        }
    }
    float s = xv / (1.0f + __expf(-xv));  // silu
    __hip_bfloat16 shi = __float2bfloat16(s);
    __hip_bfloat16 slo = __float2bfloat16(s - __bfloat162float(shi));

    __align__(16) __hip_bfloat16 row[KPI];
#pragma unroll
    for (int k = 0; k < NSPL; ++k) row[k] = __float2bfloat16(B[k]);
    row[8]  = shi;
    row[9]  = shi;
    row[10] = slo;
    row[11] = __float2bfloat16(0.0f);

    uint2* d = (uint2*)dst;
    const uint2* srow = (const uint2*)row;
    d[0] = srow[0]; d[1] = srow[1]; d[2] = srow[2];
}

__device__ __forceinline__ void wt_row_core(const float* __restrict__ coef,
                                            const float* __restrict__ sb,
                                            const float* __restrict__ sp,
                                            int i, int o,
                                            __hip_bfloat16* __restrict__ W) {
    float sbv = sb[i * O_DIM + o];
    float spv = sp[i * O_DIM + o];
    const float* cf = coef + (size_t)(i * O_DIM + o) * NSPL;
    __align__(16) __hip_bfloat16 row[KPI];
#pragma unroll
    for (int k = 0; k < NSPL; ++k) row[k] = __float2bfloat16(spv * cf[k]);
    __hip_bfloat16 whi = __float2bfloat16(sbv);
    __hip_bfloat16 wlo = __float2bfloat16(sbv - __bfloat162float(whi));
    row[8]  = whi;
    row[9]  = wlo;
    row[10] = whi;
    row[11] = __float2bfloat16(0.0f);
    uint2* dst = (uint2*)(W + (size_t)o * KDIM + i * KPI);
    const uint2* src = (const uint2*)row;
    dst[0] = src[0]; dst[1] = src[1]; dst[2] = src[2];
}

// ---------------------------------------------------------------------------
// prep: one launch for Wt-build (all 3 layers) + layer-0 features.
// Wt job: per block a (64 i x 4 o) tile of one layer; lane map i=i0+(t>>2),
// o=o0+(t&3) -> 4 consecutive lanes read one FULL 128B line of coef.
// ---------------------------------------------------------------------------
#define WT_BLOCKS   3072   // 3 layers x (8 i-tiles x 128 o-tiles)
#define FEAT_BLOCKS 2048   // NBATCH*I_DIM / 256
__global__ __launch_bounds__(256)
void prep_kernel(const float* __restrict__ x0, const float* __restrict__ gr0,
                 const float* __restrict__ c0, const float* __restrict__ sb0, const float* __restrict__ sp0,
                 const float* __restrict__ c1, const float* __restrict__ sb1, const float* __restrict__ sp1,
                 const float* __restrict__ c2, const float* __restrict__ sb2, const float* __restrict__ sp2,
                 __hip_bfloat16* __restrict__ Wt,   // [3][O_DIM][KDIM]
                 __hip_bfloat16* __restrict__ F) {  // [NBATCH][KDIM]
    int b = blockIdx.x;
    int t = threadIdx.x;
    if (b < WT_BLOCKS) {
        int l   = b >> 10;            // 0..2
        int rem = b & 1023;
        int i0  = (rem & 7) * 64;     // 8 i-tiles
        int o0  = (rem >> 3) * 4;     // 128 o-tiles
        const float* coef = l == 0 ? c0  : (l == 1 ? c1  : c2);
        const float* sb   = l == 0 ? sb0 : (l == 1 ? sb1 : sb2);
        const float* sp   = l == 0 ? sp0 : (l == 1 ? sp1 : sp2);
        wt_row_core(coef, sb, sp, i0 + (t >> 2), o0 + (t & 3),
                    Wt + (size_t)l * O_DIM * KDIM);
    } else {
        int e = (b - WT_BLOCKS) * 256 + t;   // b*512+i over [0, NBATCH*I_DIM)
        features_core(x0[e], gr0, e & (I_DIM - 1), F + (size_t)e * KPI);
    }
}

// ---------------------------------------------------------------------------
// featsum: x = sum of SPLITK partials, then features. reduce: final splitK sum.
// ---------------------------------------------------------------------------
__global__ __launch_bounds__(256)
void build_features_sum(const float* __restrict__ P,  // [SPLITK][NBATCH*I_DIM]
                        const float* __restrict__ grid,
                        __hip_bfloat16* __restrict__ F) {
    int tid = blockIdx.x * blockDim.x + threadIdx.x;
    float xv = 0.f;
#pragma unroll
    for (int s = 0; s < SPLITK; ++s) xv += P[(size_t)s * NBATCH * I_DIM + tid];
    features_core(xv, grid, tid & (I_DIM - 1), F + (size_t)tid * KPI);
}

__global__ __launch_bounds__(256)
void reduce_out(const float* __restrict__ P, float* __restrict__ out) {
    int tid = blockIdx.x * blockDim.x + threadIdx.x;
    float v = 0.f;
#pragma unroll
    for (int s = 0; s < SPLITK; ++s) v += P[(size_t)s * NBATCH * O_DIM + tid];
    out[tid] = v;
}

// ---------------------------------------------------------------------------
// GEMM: P[ks][b,o] = sum_{k in seg ks} F[b,k] * Wt[o][k]   (bf16 MFMA, fp32 acc)
// R6: verified R1 internals (single-buffer, BM=128 x BN=64, 4 waves, wave
// tile 64x32 acc[4][2], splitK=8, XOR-swizzled LDS, global_load_lds w16,
// 2 blocks/CU) + XCD-EXCLUSIVE WORK PARTITION: flat 512-block grid, and
//   ks = bid & 7   (round-robin dispatch => bid&7 == XCD id)
//   bm,bn = bid>>3 (8 bm x 8 bn = 64 tiles per XCD)
// Each XCD owns one full ks-slice: working set 8 A-segs + 8 B-segs = 2.4 MB
// < 4 MiB L2, every A/B byte crosses L3 exactly ONCE (19 MB vs 200 MB);
// the ~150 MB of tile re-reads now come from XCD-local L2 (~34.5 TB/s).
// ---------------------------------------------------------------------------
__global__ __launch_bounds__(256)
void gemm_kernel(const __hip_bfloat16* __restrict__ A,   // [NBATCH][KDIM]
                 const __hip_bfloat16* __restrict__ Wt,  // [O_DIM][KDIM]
                 float* __restrict__ P) {                // [SPLITK][NBATCH][O_DIM]
    __shared__ __hip_bfloat16 lA[BM * BK];   // 16 KB
    __shared__ __hip_bfloat16 lB[BN * BK];   // 8 KB

    int bid = blockIdx.x;
    int ks  = bid & 7;          // == XCD id under round-robin dispatch
    int slot = bid >> 3;        // 0..63 within this XCD
    int bm  = slot >> 3;        // 0..7
    int bn  = slot & 7;         // 0..7
    int tid = threadIdx.x;
    int lane = tid & 63;
    int wave = tid >> 6;
    int wr = (wave & 1) * 64;   // 2 waves along M
    int wc = (wave >> 1) * 32;  // 2 waves along N
    int q  = lane >> 4;         // 0..3
    int ln = lane & 15;

    f32x4 acc[4][2];
#pragma unroll
    for (int a = 0; a < 4; ++a)
#pragma unroll
        for (int b = 0; b < 2; ++b) acc[a][b] = (f32x4){0.f, 0.f, 0.f, 0.f};

    const __hip_bfloat16* Abase = A  + (size_t)(bm * BM) * KDIM + ks * KSEG;
    const __hip_bfloat16* Bbase = Wt + (size_t)(bn * BN) * KDIM + ks * KSEG;

    for (int kt = 0; kt < KSEG; kt += BK) {
        __syncthreads();
        // A: 1024 chunks of 16B (128 rows x 8); wave w covers [w*256, w*256+256)
        // in 4 calls. LDS dest wave-uniform base (HW adds lane*16); source
        // chunk j = (pos&7) ^ (row&7) (XOR swizzle).
#pragma unroll
        for (int c = 0; c < 4; ++c) {
            int cc = wave * 256 + c * 64 + lane;
            int r = cc >> 3, j = (cc & 7) ^ (r & 7);
            gload_lds16(Abase + (size_t)r * KDIM + kt + j * 8,
                        lA + (size_t)(wave * 256 + c * 64) * 8);
        }
        // B: 512 chunks (64 rows x 8); wave w covers [w*128, w*128+128) in 2 calls.
#pragma unroll
        for (int c = 0; c < 2; ++c) {
            int cc = wave * 128 + c * 64 + lane;
            int r = cc >> 3, j = (cc & 7) ^ (r & 7);
            gload_lds16(Bbase + (size_t)r * KDIM + kt + j * 8,
                        lB + (size_t)(wave * 128 + c * 64) * 8);
        }
        __syncthreads();   // vmcnt(0) drain before s_barrier

#pragma unroll
        for (int kh = 0; kh < 2; ++kh) {
            bf16x8 af[4], bfr[2];
#pragma unroll
            for (int rt = 0; rt < 4; ++rt) {
                int row = wr + rt * 16 + ln;
                af[rt] = *(const bf16x8*)(lA + row * BK + (((kh * 4 + q) ^ (row & 7)) * 8));
            }
#pragma unroll
            for (int ct = 0; ct < 2; ++ct) {
                int row = wc + ct * 16 + ln;
                bfr[ct] = *(const bf16x8*)(lB + row * BK + (((kh * 4 + q) ^ (row & 7)) * 8));
            }
#pragma unroll
            for (int rt = 0; rt < 4; ++rt)
#pragma unroll
                for (int ct = 0; ct < 2; ++ct)
                    acc[rt][ct] = __builtin_amdgcn_mfma_f32_16x16x32_bf16(
                        af[rt], bfr[ct], acc[rt][ct], 0, 0, 0);
        }
    }

    // epilogue: C/D layout col = lane&15, row = quad*4 + reg (round-0 verified)
    float* Pp = P + (size_t)ks * NBATCH * O_DIM;
    int orow = bm * BM + wr;
    int ocol = bn * BN + wc + ln;
#pragma unroll
    for (int rt = 0; rt < 4; ++rt)
#pragma unroll
        for (int ct = 0; ct < 2; ++ct)
#pragma unroll
            for (int r = 0; r < 4; ++r)
                Pp[(size_t)(orow + rt * 16 + q * 4 + r) * O_DIM + ocol + ct * 16]
                    = acc[rt][ct][r];
}

// ---------------------------------------------------------------------------
extern "C" void kernel_launch(void* const* d_in, const int* in_sizes, int n_in,
                              void* d_out, int out_size, void* d_ws, size_t ws_size,
                              hipStream_t stream) {
    const float* x0  = (const float*)d_in[0];
    const float* gr0 = (const float*)d_in[1];
    const float* c0  = (const float*)d_in[2];
    const float* sb0 = (const float*)d_in[3];
    const float* sp0 = (const float*)d_in[4];
    const float* gr1 = (const float*)d_in[5];
    const float* c1  = (const float*)d_in[6];
    const float* sb1 = (const float*)d_in[7];
    const float* sp1 = (const float*)d_in[8];
    const float* gr2 = (const float*)d_in[9];
    const float* c2  = (const float*)d_in[10];
    const float* sb2 = (const float*)d_in[11];
    const float* sp2 = (const float*)d_in[12];

    char* ws = (char*)d_ws;
    const size_t wt_bytes = (size_t)O_DIM * KDIM * sizeof(__hip_bfloat16);   // 6.3 MB/layer
    const size_t f_bytes  = (size_t)NBATCH * KDIM * sizeof(__hip_bfloat16);  // 12.6 MB
    __hip_bfloat16* Wt = (__hip_bfloat16*)ws;                  // 3 layers contiguous
    __hip_bfloat16* F  = (__hip_bfloat16*)(ws + 3 * wt_bytes);
    float* P = (float*)(ws + 3 * wt_bytes + f_bytes);          // [8][1024][512] = 16.8 MB
    float* out = (float*)d_out;

    prep_kernel<<<WT_BLOCKS + FEAT_BLOCKS, 256, 0, stream>>>(
        x0, gr0, c0, sb0, sp0, c1, sb1, sp1, c2, sb2, sp2, Wt, F);

    gemm_kernel<<<512, 256, 0, stream>>>(F, Wt, P);

    build_features_sum<<<(NBATCH * I_DIM) / 256, 256, 0, stream>>>(P, gr1, F);
    gemm_kernel<<<512, 256, 0, stream>>>(F, Wt + (size_t)O_DIM * KDIM, P);

    build_features_sum<<<(NBATCH * I_DIM) / 256, 256, 0, stream>>>(P, gr2, F);
    gemm_kernel<<<512, 256, 0, stream>>>(F, Wt + (size_t)2 * O_DIM * KDIM, P);

    reduce_out<<<(NBATCH * O_DIM) / 256, 256, 0, stream>>>(P, out);
}